// Round 8
// baseline (285.513 us; speedup 1.0000x reference)
//
#include <hip/hip_runtime.h>
#include <math.h>

#define NN 262144
#define DD 128
#define EPS_SL 1e-8f
#define EPS_LN 1e-5f
#define THREADS 256
#define TILE_M 32
#define NBLOCKS 512
#define TPB 16                         // tiles per block: 512*16*32 = NN

typedef __attribute__((ext_vector_type(8))) short bf16x8;
typedef __attribute__((ext_vector_type(4))) float f32x4;

// fast-path LDS: X[36][32][8] bf16 (XOR-swizzled) + H[16][32][8] + red
#define OFF_X   0                      // 18432 B
#define OFF_H   18432                  // 8192 B
#define OFF_RED 26624                  // 128 float2 = 1024 B
#define SMEM_TOT 27648                 // 2 blocks/CU easily

// fallback LDS (round-4 proven path, weights in LDS, 512 thr)
#define FB_OFF_W1 0
#define FB_OFF_W2 73728
#define FB_OFF_X  106496
#define FB_OFF_H  143360
#define FB_OFF_RED 159744
#define FB_SMEM_TOT 161792

// d_ws layout
#define WS_OFFS   0                    // (NN+1) int
#define WS_CURSOR 1048832              // NN int
#define WS_BSUM   2097408              // 1024 int
#define WS_ESRC   2101504              // E int
#define WS_WFRAG  4198656              // 52*128 uint4 = 106496 B
#define WS_NEEDED (4198656 + 106496)

__device__ inline unsigned short f2bf(float f) {
    union { float f; unsigned int i; } v; v.f = f;
    unsigned int r = v.i + 0x7fffu + ((v.i >> 16) & 1u);
    return (unsigned short)(r >> 16);
}
__device__ inline float bf2f(unsigned short u) {
    union { float f; unsigned int i; } v; v.i = ((unsigned int)u) << 16; return v.f;
}
__device__ inline unsigned int pack2(float a, float b) {
    return (unsigned int)f2bf(a) | ((unsigned int)f2bf(b) << 16);
}
__device__ inline uint4 pack8(float4 a, float4 b) {
    return make_uint4(pack2(a.x, a.y), pack2(a.z, a.w),
                      pack2(b.x, b.y), pack2(b.z, b.w));
}
__device__ inline float signed_log(float x) {
    float l = __logf(fabsf(x) + EPS_SL);
    return (x > 0.f) ? l : ((x < 0.f) ? -l : 0.f);
}
// 32-row swizzled X: unit (kb*32+row) ^ (kb&7)
__device__ inline void stx32(unsigned short* sX, int kb, int row, uint4 v) {
    *(uint4*)(sX + (((kb * 32 + row) ^ (kb & 7)) * 8)) = v;
}
__device__ inline bf16x8 ldx32(const unsigned short* sX, int kb, int row) {
    return *(const bf16x8*)(sX + (((kb * 32 + row) ^ (kb & 7)) * 8));
}
__device__ inline float ldx32_elem(const unsigned short* sX, int kb, int row, int e) {
    return bf2f(sX[(((kb * 32 + row) ^ (kb & 7)) * 8) + e]);
}
// 64-row variants (fallback kernel)
__device__ inline void stx64(unsigned short* sX, int kb, int row, uint4 v) {
    *(uint4*)(sX + (((kb * 64 + row) ^ (kb & 7)) * 8)) = v;
}
__device__ inline bf16x8 ldx64(const unsigned short* sX, int kb, int row) {
    return *(const bf16x8*)(sX + (((kb * 64 + row) ^ (kb & 7)) * 8));
}

// ---------------- CSR build ----------------
__global__ void hist_kernel(const int* __restrict__ dst, int* counts, int E) {
    int e = blockIdx.x * blockDim.x + threadIdx.x;
    if (e < E) atomicAdd(&counts[dst[e]], 1);
}

__global__ void scan_local(int* offs, int* bsum) {
    __shared__ int tmp[256];
    int t = threadIdx.x, i = blockIdx.x * 256 + t;
    int own = offs[i];
    tmp[t] = own;
    __syncthreads();
    for (int off = 1; off < 256; off <<= 1) {
        int v = (t >= off) ? tmp[t - off] : 0;
        __syncthreads();
        tmp[t] += v;
        __syncthreads();
    }
    offs[i] = tmp[t] - own;
    if (t == 255) bsum[blockIdx.x] = tmp[255];
}

__global__ void scan_bsum(int* bsum) {
    __shared__ int tmp[1024];
    int t = threadIdx.x;
    int own = bsum[t];
    tmp[t] = own;
    __syncthreads();
    for (int off = 1; off < 1024; off <<= 1) {
        int v = (t >= off) ? tmp[t - off] : 0;
        __syncthreads();
        tmp[t] += v;
        __syncthreads();
    }
    bsum[t] = tmp[t] - own;
}

__global__ void scan_fixup(int* offs, const int* __restrict__ bsum, int* cursor, int E) {
    int i = blockIdx.x * 256 + threadIdx.x;
    int v = offs[i] + bsum[i >> 8];
    offs[i] = v;
    cursor[i] = v;
    if (i == 0) offs[NN] = E;
}

__global__ void fill_kernel(const int* __restrict__ src, const int* __restrict__ dst,
                            int* cursor, int* esrc, int E) {
    int e = blockIdx.x * blockDim.x + threadIdx.x;
    if (e < E) {
        int p = atomicAdd(&cursor[dst[e]], 1);
        esrc[p] = src[e];
    }
}

// ---------------- weight prep: bf16 fragment layout into ws ----------------
// wfrag[kb*128+n]: kb 0..35 = W1 (K padded to 288), kb 36..51 = W2
__global__ void prep_weights(const float* __restrict__ W1, const float* __restrict__ W2,
                             uint4* wfrag) {
    int t = blockIdx.x * blockDim.x + threadIdx.x;
    if (t >= 52 * 128) return;
    int kb = t >> 7, n = t & 127;
    unsigned short tmp[8] __attribute__((aligned(16)));
    if (kb < 36) {
        #pragma unroll
        for (int j = 0; j < 8; ++j) {
            int k = kb * 8 + j;
            tmp[j] = (k < 261) ? f2bf(W1[k * DD + n]) : (unsigned short)0;
        }
    } else {
        int kb2 = kb - 36;
        #pragma unroll
        for (int j = 0; j < 8; ++j) tmp[j] = f2bf(W2[(kb2 * 8 + j) * DD + n]);
    }
    wfrag[t] = *(const uint4*)tmp;
}

// ---- CSR gather -> upstream bf16 (one row per 512B out slot, r4-proven) ----
__global__ __launch_bounds__(256) void gather_kernel(
    const float4* __restrict__ h4, const int* __restrict__ offs,
    const int* __restrict__ esrc, char* outb)
{
    int stride = gridDim.x * 256;
    for (int idx = blockIdx.x * 256 + threadIdx.x; idx < NN * 16; idx += stride) {
        int n = idx >> 4, c = idx & 15;
        int o0 = offs[n], o1 = offs[n + 1];
        float4 a = make_float4(0.f, 0.f, 0.f, 0.f);
        float4 b = make_float4(0.f, 0.f, 0.f, 0.f);
        for (int e = o0; e < o1; ++e) {
            const float4* hr = h4 + (size_t)esrc[e] * 32 + c * 2;
            float4 p0 = hr[0], p1 = hr[1];
            a.x += p0.x; a.y += p0.y; a.z += p0.z; a.w += p0.w;
            b.x += p1.x; b.y += p1.y; b.z += p1.z; b.w += p1.w;
        }
        *(uint4*)(outb + (size_t)n * 512 + c * 16) = pack8(a, b);
    }
}

// ---------------- fallback atomic scatter ----------------
__global__ void scatter_kernel(const float4* __restrict__ h4,
                               const int* __restrict__ src,
                               const int* __restrict__ dst,
                               float* up, int E) {
    int tid = blockIdx.x * blockDim.x + threadIdx.x;
    int e = tid >> 5;
    if (e >= E) return;
    int c = tid & 31;
    float4 v = h4[(size_t)src[e] * 32 + c];
    float* o = up + (size_t)dst[e] * DD + c * 4;
    atomicAdd(o + 0, v.x);
    atomicAdd(o + 1, v.y);
    atomicAdd(o + 2, v.z);
    atomicAdd(o + 3, v.w);
}

// ======== fast path: reg-weight MFMA node MLP + LN, 256thr, 2 blk/CU ========
// up = bf16 slots at (char*)out + n*512. Aliasing safe: block reads only its
// own tiles' slots (prefetch) before overwriting those rows with output.
__global__ __launch_bounds__(THREADS, 2) void node_kernel(
    const float* __restrict__ h, const void* up,
    const uint4* __restrict__ wfrag,
    const float* __restrict__ c1, const float* __restrict__ c2,
    const float* __restrict__ c3, const float* __restrict__ c4,
    const float* __restrict__ qn,
    const float* __restrict__ b1, const float* __restrict__ b2,
    const float* __restrict__ gamma, const float* __restrict__ beta,
    float* out)
{
    __shared__ char smem[SMEM_TOT];
    unsigned short* sX = (unsigned short*)(smem + OFF_X);
    unsigned short* sH = (unsigned short*)(smem + OFF_H);
    float2* red = (float2*)(smem + OFF_RED);

    const int tid  = threadIdx.x;
    const int lane = tid & 63;
    const int wv   = tid >> 6;     // 0..3: column quarter
    const int l15  = lane & 15;
    const int lk   = lane >> 4;    // 0..3
    const int col0 = wv * 32 + l15;
    const int col1 = col0 + 16;

    // ---- preload loop-invariant weight fragments into registers ----
    bf16x8 w1r[9][2], w2r[4][2];
    #pragma unroll
    for (int ks = 0; ks < 9; ++ks) {
        int kb = ks * 4 + lk;
        w1r[ks][0] = *(const bf16x8*)(wfrag + kb * 128 + col0);
        w1r[ks][1] = *(const bf16x8*)(wfrag + kb * 128 + col1);
    }
    #pragma unroll
    for (int ks = 0; ks < 4; ++ks) {
        int kb = 36 + ks * 4 + lk;
        w2r[ks][0] = *(const bf16x8*)(wfrag + kb * 128 + col0);
        w2r[ks][1] = *(const bf16x8*)(wfrag + kb * 128 + col1);
    }

    const float b1v[2] = {b1[col0], b1[col1]};
    const float b2v[2] = {b2[col0], b2[col1]};
    const float gv[2]  = {gamma[col0], gamma[col1]};
    const float bv[2]  = {beta[col0], beta[col1]};

    // zero pad kb 33..35 (3*32 = 96 units)
    if (tid < 96) stx32(sX, 33 + (tid >> 5), tid & 31, make_uint4(0u, 0u, 0u, 0u));

    // staging chunk: thread owns (k0, r0) and (k0, r0+16), k0 0..15, r0 0..15
    const int k0 = tid & 15;
    const int r0 = tid >> 4;

    float4 h0a, h0b, h1a, h1b;     // fp32 h chunks (rows r0, r0+16)
    uint4  u0, u1;                 // bf16 upstream slot chunks
    float pc1 = 0.f, pc2 = 0.f, pc3 = 0.f, pc4 = 0.f, pc5 = 0.f;

    const int tile0 = blockIdx.x * TPB;

    // ---- prologue prefetch: tile 0 ----
    {
        int base = tile0 * TILE_M;
        const float* hp = h + (size_t)(base + r0) * DD + k0 * 8;
        h0a = *(const float4*)hp;             h0b = *(const float4*)(hp + 4);
        h1a = *(const float4*)(hp + 16 * DD); h1b = *(const float4*)(hp + 16 * DD + 4);
        const char* ub = (const char*)up;
        u0 = *(const uint4*)(ub + (size_t)(base + r0) * 512 + k0 * 16);
        u1 = *(const uint4*)(ub + (size_t)(base + r0 + 16) * 512 + k0 * 16);
        if (tid < 32) {
            int n0 = base + tid;
            pc1 = c1[n0]; pc2 = c2[n0]; pc3 = c3[n0]; pc4 = c4[n0]; pc5 = qn[n0];
        }
    }
    __syncthreads();

    for (int tt = 0; tt < TPB; ++tt) {
        const int base = (tile0 + tt) * TILE_M;

        // ---- write prefetched regs -> sX ----
        stx32(sX, k0, r0,           pack8(h0a, h0b));
        stx32(sX, k0, r0 + 16,      pack8(h1a, h1b));
        stx32(sX, 16 + k0, r0,      u0);
        stx32(sX, 16 + k0, r0 + 16, u1);
        if (tid < 32) {
            uint4 pv = make_uint4(pack2(signed_log(pc1), signed_log(pc2)),
                                  pack2(signed_log(pc3), signed_log(pc4)),
                                  pack2(signed_log(pc5), 0.f), 0u);
            stx32(sX, 32, tid, pv);
        }

        // ---- issue next-tile prefetch (overlaps GEMM + epilogue) ----
        if (tt + 1 < TPB) {
            int bn = base + TILE_M;
            const float* hp = h + (size_t)(bn + r0) * DD + k0 * 8;
            h0a = *(const float4*)hp;             h0b = *(const float4*)(hp + 4);
            h1a = *(const float4*)(hp + 16 * DD); h1b = *(const float4*)(hp + 16 * DD + 4);
            const char* ub = (const char*)up;
            u0 = *(const uint4*)(ub + (size_t)(bn + r0) * 512 + k0 * 16);
            u1 = *(const uint4*)(ub + (size_t)(bn + r0 + 16) * 512 + k0 * 16);
            if (tid < 32) {
                int n0 = bn + tid;
                pc1 = c1[n0]; pc2 = c2[n0]; pc3 = c3[n0]; pc4 = c4[n0]; pc5 = qn[n0];
            }
        }
        __syncthreads();   // sX ready

        // ---- GEMM1: (32x288) @ (288x128); B from registers ----
        f32x4 acc[2][2] = {};
        #pragma unroll
        for (int ks = 0; ks < 9; ++ks) {
            int kb = ks * 4 + lk;
            bf16x8 a0 = ldx32(sX, kb, l15);
            bf16x8 a1 = ldx32(sX, kb, 16 + l15);
            acc[0][0] = __builtin_amdgcn_mfma_f32_16x16x32_bf16(a0, w1r[ks][0], acc[0][0], 0, 0, 0);
            acc[0][1] = __builtin_amdgcn_mfma_f32_16x16x32_bf16(a0, w1r[ks][1], acc[0][1], 0, 0, 0);
            acc[1][0] = __builtin_amdgcn_mfma_f32_16x16x32_bf16(a1, w1r[ks][0], acc[1][0], 0, 0, 0);
            acc[1][1] = __builtin_amdgcn_mfma_f32_16x16x32_bf16(a1, w1r[ks][1], acc[1][1], 0, 0, 0);
        }
        // silu -> hid tile (bf16, subtiled [16][32][8])
        #pragma unroll
        for (int fm = 0; fm < 2; ++fm) {
            int row = fm * 16 + lk * 4;
            #pragma unroll
            for (int fn = 0; fn < 2; ++fn) {
                int col = wv * 32 + fn * 16 + l15;
                int kbh = col >> 3, ko = col & 7;
                #pragma unroll
                for (int r = 0; r < 4; ++r) {
                    float v = acc[fm][fn][r] + b1v[fn];
                    float sg = 1.f / (1.f + __expf(-v));
                    sH[(kbh * 32 + row + r) * 8 + ko] = f2bf(v * sg);
                }
            }
        }
        __syncthreads();

        // ---- GEMM2: (32x128) @ (128x128); B from registers ----
        f32x4 acc2[2][2] = {};
        #pragma unroll
        for (int ks = 0; ks < 4; ++ks) {
            int kb = ks * 4 + lk;
            bf16x8 a0 = *(const bf16x8*)(sH + (kb * 32 + l15) * 8);
            bf16x8 a1 = *(const bf16x8*)(sH + (kb * 32 + 16 + l15) * 8);
            acc2[0][0] = __builtin_amdgcn_mfma_f32_16x16x32_bf16(a0, w2r[ks][0], acc2[0][0], 0, 0, 0);
            acc2[0][1] = __builtin_amdgcn_mfma_f32_16x16x32_bf16(a0, w2r[ks][1], acc2[0][1], 0, 0, 0);
            acc2[1][0] = __builtin_amdgcn_mfma_f32_16x16x32_bf16(a1, w2r[ks][0], acc2[1][0], 0, 0, 0);
            acc2[1][1] = __builtin_amdgcn_mfma_f32_16x16x32_bf16(a1, w2r[ks][1], acc2[1][1], 0, 0, 0);
        }

        // ---- residual (h from X tile, bf16) + LN partials ----
        const int kbc0 = col0 >> 3, ec0 = col0 & 7;
        const int kbc1 = col1 >> 3, ec1 = col1 & 7;
        float rs1[2][4], rs2[2][4];
        #pragma unroll
        for (int fm = 0; fm < 2; ++fm) {
            #pragma unroll
            for (int r = 0; r < 4; ++r) {
                int rloc = fm * 16 + lk * 4 + r;
                float z0 = acc2[fm][0][r] + b2v[0] + ldx32_elem(sX, kbc0, rloc, ec0);
                float z1 = acc2[fm][1][r] + b2v[1] + ldx32_elem(sX, kbc1, rloc, ec1);
                acc2[fm][0][r] = z0; acc2[fm][1][r] = z1;
                float s = z0 + z1, q = z0 * z0 + z1 * z1;
                #pragma unroll
                for (int off = 1; off < 16; off <<= 1) {
                    s += __shfl_xor(s, off);
                    q += __shfl_xor(q, off);
                }
                rs1[fm][r] = s; rs2[fm][r] = q;
            }
        }
        if (l15 == 0) {
            #pragma unroll
            for (int fm = 0; fm < 2; ++fm)
                #pragma unroll
                for (int r = 0; r < 4; ++r)
                    red[wv * 32 + fm * 16 + lk * 4 + r] = make_float2(rs1[fm][r], rs2[fm][r]);
        }
        __syncthreads();

        #pragma unroll
        for (int fm = 0; fm < 2; ++fm) {
            #pragma unroll
            for (int r = 0; r < 4; ++r) {
                int rloc = fm * 16 + lk * 4 + r;
                float2 t0 = red[rloc], t1 = red[32 + rloc],
                       t2 = red[64 + rloc], t3 = red[96 + rloc];
                float S = t0.x + t1.x + t2.x + t3.x;
                float Q = t0.y + t1.y + t2.y + t3.y;
                float mean = S * (1.f / 128.f);
                float var  = Q * (1.f / 128.f) - mean * mean;
                float rstd = rsqrtf(var + EPS_LN);
                size_t rowg = (size_t)(base + rloc) * DD;
                out[rowg + col0] = (acc2[fm][0][r] - mean) * rstd * gv[0] + bv[0];
                out[rowg + col1] = (acc2[fm][1][r] - mean) * rstd * gv[1] + bv[1];
            }
        }
        // loop back: next stx is 2+ barriers after this tile's last sX read
    }
}

// ============ fallback (ws too small): r4-proven LDS-weight path ============
__global__ __launch_bounds__(512) void node_kernel_fb(
    const float* __restrict__ h, const float* up,
    const float* __restrict__ c1, const float* __restrict__ c2,
    const float* __restrict__ c3, const float* __restrict__ c4,
    const float* __restrict__ qn,
    const float* __restrict__ W1, const float* __restrict__ b1,
    const float* __restrict__ W2, const float* __restrict__ b2,
    const float* __restrict__ gamma, const float* __restrict__ beta,
    float* out)
{
    extern __shared__ char smem[];
    unsigned short* sW1 = (unsigned short*)(smem + FB_OFF_W1);
    unsigned short* sW2 = (unsigned short*)(smem + FB_OFF_W2);
    unsigned short* sX  = (unsigned short*)(smem + FB_OFF_X);
    unsigned short* sH  = (unsigned short*)(smem + FB_OFF_H);
    float2* red = (float2*)(smem + FB_OFF_RED);

    const int tid = threadIdx.x;

    for (int c = tid; c < 36 * 128; c += 512) {
        int kb = c >> 7, n = c & 127;
        unsigned short tmp[8] __attribute__((aligned(16)));
        #pragma unroll
        for (int j = 0; j < 8; ++j) {
            int k = kb * 8 + j;
            tmp[j] = (k < 261) ? f2bf(W1[k * DD + n]) : (unsigned short)0;
        }
        *(uint4*)(sW1 + c * 8) = *(const uint4*)tmp;
    }
    for (int c = tid; c < 16 * 128; c += 512) {
        int kb = c >> 7, n = c & 127;
        unsigned short tmp[8] __attribute__((aligned(16)));
        #pragma unroll
        for (int j = 0; j < 8; ++j) tmp[j] = f2bf(W2[(kb * 8 + j) * DD + n]);
        *(uint4*)(sW2 + c * 8) = *(const uint4*)tmp;
    }
    if (tid < 192) {
        int kb = 33 + (tid >> 6), row = tid & 63;
        stx64(sX, kb, row, make_uint4(0u, 0u, 0u, 0u));
    }

    const int lane = tid & 63;
    const int w    = tid >> 6;
    const int wm   = w >> 2;
    const int wn   = w & 3;
    const int l15  = lane & 15;
    const int lk   = lane >> 4;
    const int col0 = wn * 32 + l15;
    const int col1 = col0 + 16;

    const float b1v[2] = {b1[col0], b1[col1]};
    const float b2v[2] = {b2[col0], b2[col1]};
    const float gv[2]  = {gamma[col0], gamma[col1]};
    const float bv[2]  = {beta[col0], beta[col1]};

    const bf16x8* W1f = (const bf16x8*)sW1;
    const bf16x8* Hf  = (const bf16x8*)sH;
    const bf16x8* W2f = (const bf16x8*)sW2;

    const int k0 = tid & 15;
    const int r0 = tid >> 4;
    const int FB_TPB = 16;

    float4 h0a, h0b, h1a, h1b, v0a, v0b, v1a, v1b;
    float pc1 = 0.f, pc2 = 0.f, pc3 = 0.f, pc4 = 0.f, pc5 = 0.f;

    {
        int base = blockIdx.x * FB_TPB * 64;
        const float* hp = h + (size_t)(base + r0) * DD + k0 * 8;
        h0a = *(const float4*)hp;             h0b = *(const float4*)(hp + 4);
        h1a = *(const float4*)(hp + 32 * DD); h1b = *(const float4*)(hp + 32 * DD + 4);
        const float* uf = up + (size_t)(base + r0) * DD + k0 * 8;
        v0a = *(const float4*)uf;             v0b = *(const float4*)(uf + 4);
        v1a = *(const float4*)(uf + 32 * DD); v1b = *(const float4*)(uf + 32 * DD + 4);
        if (tid < 64) {
            int n0 = base + tid;
            pc1 = c1[n0]; pc2 = c2[n0]; pc3 = c3[n0]; pc4 = c4[n0]; pc5 = qn[n0];
        }
    }
    __syncthreads();

    for (int tt = 0; tt < FB_TPB; ++tt) {
        const int base = (blockIdx.x * FB_TPB + tt) * 64;

        stx64(sX, k0, r0,           pack8(h0a, h0b));
        stx64(sX, k0, r0 + 32,      pack8(h1a, h1b));
        stx64(sX, 16 + k0, r0,      pack8(v0a, v0b));
        stx64(sX, 16 + k0, r0 + 32, pack8(v1a, v1b));
        if (tid < 64) {
            uint4 pv = make_uint4(pack2(signed_log(pc1), signed_log(pc2)),
                                  pack2(signed_log(pc3), signed_log(pc4)),
                                  pack2(signed_log(pc5), 0.f), 0u);
            stx64(sX, 32, tid, pv);
        }
        if (tt + 1 < FB_TPB) {
            int bn = base + 64;
            const float* hp = h + (size_t)(bn + r0) * DD + k0 * 8;
            h0a = *(const float4*)hp;             h0b = *(const float4*)(hp + 4);
            h1a = *(const float4*)(hp + 32 * DD); h1b = *(const float4*)(hp + 32 * DD + 4);
            const float* uf = up + (size_t)(bn + r0) * DD + k0 * 8;
            v0a = *(const float4*)uf;             v0b = *(const float4*)(uf + 4);
            v1a = *(const float4*)(uf + 32 * DD); v1b = *(const float4*)(uf + 32 * DD + 4);
            if (tid < 64) {
                int n0 = bn + tid;
                pc1 = c1[n0]; pc2 = c2[n0]; pc3 = c3[n0]; pc4 = c4[n0]; pc5 = qn[n0];
            }
        }
        __syncthreads();

        f32x4 acc[2][2] = {};
        #pragma unroll
        for (int ks = 0; ks < 9; ++ks) {
            int kb = ks * 4 + lk;
            bf16x8 a0  = ldx64(sX, kb, wm * 32 + l15);
            bf16x8 a1  = ldx64(sX, kb, wm * 32 + 16 + l15);
            bf16x8 bb0 = W1f[kb * 128 + col0];
            bf16x8 bb1 = W1f[kb * 128 + col1];
            acc[0][0] = __builtin_amdgcn_mfma_f32_16x16x32_bf16(a0, bb0, acc[0][0], 0, 0, 0);
            acc[0][1] = __builtin_amdgcn_mfma_f32_16x16x32_bf16(a0, bb1, acc[0][1], 0, 0, 0);
            acc[1][0] = __builtin_amdgcn_mfma_f32_16x16x32_bf16(a1, bb0, acc[1][0], 0, 0, 0);
            acc[1][1] = __builtin_amdgcn_mfma_f32_16x16x32_bf16(a1, bb1, acc[1][1], 0, 0, 0);
        }
        #pragma unroll
        for (int fm = 0; fm < 2; ++fm) {
            int row = wm * 32 + fm * 16 + lk * 4;
            #pragma unroll
            for (int fn = 0; fn < 2; ++fn) {
                int col = wn * 32 + fn * 16 + l15;
                int kbh = col >> 3, ko = col & 7;
                #pragma unroll
                for (int r = 0; r < 4; ++r) {
                    float v = acc[fm][fn][r] + b1v[fn];
                    float sg = 1.f / (1.f + __expf(-v));
                    sH[(kbh * 64 + row + r) * 8 + ko] = f2bf(v * sg);
                }
            }
        }
        __syncthreads();

        f32x4 acc2[2][2] = {};
        #pragma unroll
        for (int ks = 0; ks < 4; ++ks) {
            int kb = ks * 4 + lk;
            bf16x8 a0  = Hf[kb * 64 + wm * 32 + l15];
            bf16x8 a1  = Hf[kb * 64 + wm * 32 + 16 + l15];
            bf16x8 bb0 = W2f[kb * 128 + col0];
            bf16x8 bb1 = W2f[kb * 128 + col1];
            acc2[0][0] = __builtin_amdgcn_mfma_f32_16x16x32_bf16(a0, bb0, acc2[0][0], 0, 0, 0);
            acc2[0][1] = __builtin_amdgcn_mfma_f32_16x16x32_bf16(a0, bb1, acc2[0][1], 0, 0, 0);
            acc2[1][0] = __builtin_amdgcn_mfma_f32_16x16x32_bf16(a1, bb0, acc2[1][0], 0, 0, 0);
            acc2[1][1] = __builtin_amdgcn_mfma_f32_16x16x32_bf16(a1, bb1, acc2[1][1], 0, 0, 0);
        }

        float rs1[2][4], rs2[2][4];
        #pragma unroll
        for (int fm = 0; fm < 2; ++fm) {
            #pragma unroll
            for (int r = 0; r < 4; ++r) {
                size_t rowg = (size_t)(base + wm * 32 + fm * 16 + lk * 4 + r) * DD;
                float z0 = acc2[fm][0][r] + b2v[0] + h[rowg + col0];
                float z1 = acc2[fm][1][r] + b2v[1] + h[rowg + col1];
                acc2[fm][0][r] = z0; acc2[fm][1][r] = z1;
                float s = z0 + z1, q = z0 * z0 + z1 * z1;
                #pragma unroll
                for (int off = 1; off < 16; off <<= 1) {
                    s += __shfl_xor(s, off);
                    q += __shfl_xor(q, off);
                }
                rs1[fm][r] = s; rs2[fm][r] = q;
            }
        }
        if (l15 == 0) {
            #pragma unroll
            for (int fm = 0; fm < 2; ++fm)
                #pragma unroll
                for (int r = 0; r < 4; ++r)
                    red[wn * 64 + wm * 32 + fm * 16 + lk * 4 + r] =
                        make_float2(rs1[fm][r], rs2[fm][r]);
        }
        __syncthreads();

        #pragma unroll
        for (int fm = 0; fm < 2; ++fm) {
            #pragma unroll
            for (int r = 0; r < 4; ++r) {
                int rloc = wm * 32 + fm * 16 + lk * 4 + r;
                float2 t0 = red[rloc], t1 = red[64 + rloc],
                       t2 = red[128 + rloc], t3 = red[192 + rloc];
                float S = t0.x + t1.x + t2.x + t3.x;
                float Q = t0.y + t1.y + t2.y + t3.y;
                float mean = S * (1.f / 128.f);
                float var  = Q * (1.f / 128.f) - mean * mean;
                float rstd = rsqrtf(var + EPS_LN);
                size_t rowg = (size_t)(base + rloc) * DD;
                out[rowg + col0] = (acc2[fm][0][r] - mean) * rstd * gv[0] + bv[0];
                out[rowg + col1] = (acc2[fm][1][r] - mean) * rstd * gv[1] + bv[1];
            }
        }
    }
}

extern "C" void kernel_launch(void* const* d_in, const int* in_sizes, int n_in,
                              void* d_out, int out_size, void* d_ws, size_t ws_size,
                              hipStream_t stream) {
    const float* h     = (const float*)d_in[0];
    const float* c1    = (const float*)d_in[1];
    const float* c2    = (const float*)d_in[2];
    const float* c3    = (const float*)d_in[3];
    const float* c4    = (const float*)d_in[4];
    const float* qn    = (const float*)d_in[5];
    const int*   src   = (const int*)d_in[6];
    const int*   dst   = (const int*)d_in[7];
    const float* W1    = (const float*)d_in[8];
    const float* b1    = (const float*)d_in[9];
    const float* W2    = (const float*)d_in[10];
    const float* b2    = (const float*)d_in[11];
    const float* gamma = (const float*)d_in[12];
    const float* beta  = (const float*)d_in[13];
    float* out = (float*)d_out;
    int E = in_sizes[6];

    if (ws_size >= (size_t)WS_NEEDED) {
        char* ws = (char*)d_ws;
        int* offs    = (int*)(ws + WS_OFFS);
        int* cursor  = (int*)(ws + WS_CURSOR);
        int* bsum    = (int*)(ws + WS_BSUM);
        int* esrc    = (int*)(ws + WS_ESRC);
        uint4* wfrag = (uint4*)(ws + WS_WFRAG);

        hipMemsetAsync(offs, 0, (size_t)NN * sizeof(int), stream);
        int eb = (E + 255) / 256;
        hist_kernel<<<eb, 256, 0, stream>>>(dst, offs, E);
        scan_local<<<NN / 256, 256, 0, stream>>>(offs, bsum);
        scan_bsum<<<1, 1024, 0, stream>>>(bsum);
        scan_fixup<<<NN / 256, 256, 0, stream>>>(offs, bsum, cursor, E);
        fill_kernel<<<eb, 256, 0, stream>>>(src, dst, cursor, esrc, E);
        prep_weights<<<26, 256, 0, stream>>>(W1, W2, wfrag);

        gather_kernel<<<2048, 256, 0, stream>>>((const float4*)h, offs, esrc, (char*)d_out);

        node_kernel<<<NBLOCKS, THREADS, 0, stream>>>(
            h, d_out, wfrag, c1, c2, c3, c4, qn, b1, b2, gamma, beta, out);
    } else {
        // fallback: atomic scatter into d_out (fp32 upstream), LDS-weight kernel
        hipMemsetAsync(d_out, 0, (size_t)NN * DD * sizeof(float), stream);
        int sthreads = E * 32;
        int sblocks = (sthreads + 255) / 256;
        scatter_kernel<<<sblocks, 256, 0, stream>>>((const float4*)h, src, dst, out, E);
        hipFuncSetAttribute(reinterpret_cast<const void*>(&node_kernel_fb),
                            hipFuncAttributeMaxDynamicSharedMemorySize, FB_SMEM_TOT);
        node_kernel_fb<<<256, 512, FB_SMEM_TOT, stream>>>(
            h, out, c1, c2, c3, c4, qn,
            W1, b1, W2, b2, gamma, beta, out);
    }
}